// Round 3
// baseline (903.182 us; speedup 1.0000x reference)
//
#include <hip/hip_runtime.h>
#include <math.h>

#define D_DIM 2048
#define T_DIM 128
#define TT 8    // t-values per pass (two passes per block -> 16 t per block)

// TT=8 swizzles: tt supplies only 3 bank bits, so XOR TWO row bits into
// e' bits 0,1 (bank bits 3,4).  Both are involutions; write & read use the
// same swizzle so the mapping stays consistent.
__device__ __forceinline__ int sw1(int x) { return x ^ ((x >> 5) & 3); }
__device__ __forceinline__ int sw2(int x) { return x ^ ((x >> 4) & 3); }

// radix-2 butterfly over register-index bit MM (fully unrolled, constant idx)
#define BFLY(MM)                                              \
    _Pragma("unroll")                                         \
    for (int i_ = 0; i_ < 64; ++i_) {                         \
        if ((i_ & (MM)) == 0) {                               \
            float a_ = v[i_], b_ = v[i_ | (MM)];              \
            v[i_] = a_ + b_;                                  \
            v[i_ | (MM)] = a_ - b_;                           \
        }                                                     \
    }

// launch_bounds 2nd arg: empirically hipcc caps VGPRs at 512/(2*arg)
// regardless of block size ((512,4) and (256,4) both -> 64-VGPR cap ->
// catastrophic v[64] spill, 650+ MB scratch traffic, R2 disaster).
// arg=2 -> 128-VGPR cap; kernel needs ~84 -> no spill.  Occupancy is then
// LDS-limited: 32 KiB -> 5 blocks/CU = 20 waves (62.5%).
__global__ __launch_bounds__(256, 2)
void fwht_apply_kernel(const float* __restrict__ z,
                       const float* __restrict__ d1,
                       const float* __restrict__ d2,
                       const float* __restrict__ d3,
                       const float* __restrict__ bvec,
                       const float* __restrict__ sldj_in,
                       float* __restrict__ out) {
    __shared__ float lds[1024 * TT];            // 32 KiB
    const int tid = threadIdx.x;

    if (blockIdx.x == 1024) {                   // ---- sldj block ----
        float acc = 0.0f;
        for (int i = tid; i < D_DIM; i += 256)
            acc += logf(fabsf(d1[i])) + logf(fabsf(d2[i])) + logf(fabsf(d3[i]));
        lds[tid] = acc;
        __syncthreads();
        #pragma unroll
        for (int sft = 128; sft > 0; sft >>= 1) {
            if (tid < sft) lds[tid] += lds[tid + sft];
            __syncthreads();
        }
        if (tid < 128)
            out[(size_t)4 * 32 * 2048 * 128 + tid] = sldj_in[tid] + lds[0];
        return;
    }

    const int r   = tid >> 3;                   // 5-bit "rest" coordinate (0..31)
    const int tt  = tid & 7;                    // t within tile (0..7)
    const int bid = blockIdx.x;
    // km in LOW bits: all 8 pair-blocks of a km slab share bid%8 -> same XCD,
    // so every 128B line of the slab is read/written through ONE L2.
    const int km  = bid & 127;                  // (k,m) slab (128 total)
    const int p0  = bid >> 7;                   // tile-pair index (0..7)
    const float s = 0.022097086912079608f;      // 1/sqrt(2048), one per H

    const int wid  = tid >> 6;                  // wave id (0..3)
    const int lane = tid & 63;
    const int q    = (lane >> 1) & 15;          // 4-bit row-within-run
    const int c    = lane & 1;                  // float4 slot within 32B row
    const int nl   = lane >> 5;                 // run lsb from lane bit5

    // Two passes: tiles 2*p0 and 2*p0+1.  The passes touch the two 32B
    // halves of each 64B line from the same block (same XCD L2, adjacent
    // in time) so HBM reads/writebacks stay full-line where L2 merges.
    #pragma unroll 1
    for (int p = 0; p < 2; ++p) {
        const int t0 = (p0 << 4) | (p << 3);    // tile base (16 tiles of 8)
        const float* zslab = z + ((size_t)km << 18) + t0;
        float v[64];
        __syncthreads();                        // LDS reuse across passes

        // ---- staged load: two 32KiB rounds partitioned by e-bit4.
        // Global: dwordx4, 32 rows x 32B fully-used per wave-instruction.
        // LDS row idx = (e>>5)<<4 | (e&15); word = idx*8 + t.  b128 writes
        // land at word = 4*lane (+n<<7) -> linear, conflict-free.
        #pragma unroll
        for (int h = 0; h < 2; ++h) {
            #pragma unroll
            for (int i = 0; i < 8; ++i) {
                const int n = (wid << 4) | (i << 1) | nl;   // run (0..63)
                const int e = (n << 5) | (h << 4) | q;
                float4 tmp = *(const float4*)(zslab + (size_t)e * T_DIM + (c << 2));
                ((float4*)lds)[(n << 5) + (q << 1) + c] = tmp;
            }
            __syncthreads();
            if (((r >> 4) & 1) == h) {
                // P1 read: word = j<<7 | (r&15)<<3 | tt.
                // bank = (r&3)<<3 | tt -> 32 banks over (tt,r0,r1), r2 2-way.
                #pragma unroll
                for (int j = 0; j < 64; ++j) {
                    const int e = (j << 5) | r;
                    v[j] = lds[(j << 7) + ((r & 15) << 3) + tt] * (d1[e] * s);
                }
            }
            __syncthreads();
        }

        // ---- P1: e = (j<<5)|r.  F1 on e-bits 5..10 ----
        BFLY(1) BFLY(2) BFLY(4) BFLY(8) BFLY(16) BFLY(32)

        // ---- T1: partition e-bit10 (= j5 on both sides). e' = e & 1023 ----
        #pragma unroll
        for (int j = 0; j < 32; ++j)                      // round A write (e10=0)
            lds[(sw1((j << 5) | r) << 3) + tt] = v[j];
        __syncthreads();
        #pragma unroll
        for (int j = 0; j < 32; ++j)                      // round A read: P2 map
            v[j] = lds[(sw1(j | (r << 5)) << 3) + tt];
        __syncthreads();
        #pragma unroll
        for (int j = 32; j < 64; ++j)                     // round B write (e10=1)
            lds[(sw1(((j & 31) << 5) | r) << 3) + tt] = v[j];
        __syncthreads();
        #pragma unroll
        for (int j = 32; j < 64; ++j)                     // round B read
            v[j] = lds[(sw1((j & 31) | (r << 5)) << 3) + tt];
        __syncthreads();

        // ---- P2: e = (j&31) | ((j>>5)<<10) | (r<<5) ----
        BFLY(1) BFLY(2) BFLY(4) BFLY(8) BFLY(16)          // F1 e-bits 0..4 (F1 done)
        {   // * d2 * s : per-thread e is two contiguous runs of 32 -> float4
            const float4* q0 = (const float4*)(d2 + (r << 5));
            const float4* q1 = (const float4*)(d2 + 1024 + (r << 5));
            #pragma unroll
            for (int qq = 0; qq < 8; ++qq) {
                float4 a = q0[qq];
                v[4*qq+0] *= a.x * s; v[4*qq+1] *= a.y * s;
                v[4*qq+2] *= a.z * s; v[4*qq+3] *= a.w * s;
                float4 cc = q1[qq];
                v[32+4*qq+0] *= cc.x * s; v[32+4*qq+1] *= cc.y * s;
                v[32+4*qq+2] *= cc.z * s; v[32+4*qq+3] *= cc.w * s;
            }
        }
        BFLY(1) BFLY(2) BFLY(4) BFLY(8) BFLY(16) BFLY(32) // F2 e-bits 0..4,10

        // ---- T2: partition e-bit0 (= j0 on both sides). e' = e >> 1 ----
        #pragma unroll
        for (int j = 0; j < 64; j += 2)                   // round A write (e0=0)
            lds[(sw2(((j >> 1) & 15) | (r << 4) | ((j >> 5) << 9)) << 3) + tt] = v[j];
        __syncthreads();
        #pragma unroll
        for (int j = 0; j < 64; j += 2)                   // round A read: P3 map
            v[j] = lds[(sw2((((j >> 1) & 31) << 4) | (r & 15) | ((r >> 4) << 9)) << 3) + tt];
        __syncthreads();
        #pragma unroll
        for (int j = 1; j < 64; j += 2)                   // round B write (e0=1)
            lds[(sw2(((j >> 1) & 15) | (r << 4) | ((j >> 5) << 9)) << 3) + tt] = v[j];
        __syncthreads();
        #pragma unroll
        for (int j = 1; j < 64; j += 2)                   // round B read
            v[j] = lds[(sw2((((j >> 1) & 31) << 4) | (r & 15) | ((r >> 4) << 9)) << 3) + tt];
        __syncthreads();

        // ---- P3: e = ((j>>1)<<5) | (j&1) | eRest, eRest = ((r&15)<<1)|((r>>4)<<10)
        BFLY(2) BFLY(4) BFLY(8) BFLY(16) BFLY(32)         // F2 e-bits 5..9 (F2 done)
        {   // * d3 * s : (v[2m], v[2m+1]) sit at (e, e+1) -> float2
            const int eRest = ((r & 15) << 1) | ((r >> 4) << 10);
            #pragma unroll
            for (int m = 0; m < 32; ++m) {
                float2 a = *(const float2*)(d3 + ((m << 5) | eRest));
                v[2*m]   *= a.x * s;
                v[2*m+1] *= a.y * s;
            }
        }
        BFLY(2) BFLY(4) BFLY(8) BFLY(16) BFLY(32) BFLY(1) // F3 e-bits 5..9, 0

        // ---- T3: partition e-bit0 (= j0 on both sides). e' = e >> 1 ----
        #pragma unroll
        for (int j = 0; j < 64; j += 2)                   // round A write (e0=0)
            lds[(sw2((((j >> 1) & 31) << 4) | (r & 15) | ((r >> 4) << 9)) << 3) + tt] = v[j];
        __syncthreads();
        #pragma unroll
        for (int j = 0; j < 64; j += 2)                   // round A read: P4(=P2) map
            v[j] = lds[(sw2(((j >> 1) & 15) | (r << 4) | ((j >> 5) << 9)) << 3) + tt];
        __syncthreads();
        #pragma unroll
        for (int j = 1; j < 64; j += 2)                   // round B write (e0=1)
            lds[(sw2((((j >> 1) & 31) << 4) | (r & 15) | ((r >> 4) << 9)) << 3) + tt] = v[j];
        __syncthreads();
        #pragma unroll
        for (int j = 1; j < 64; j += 2)                   // round B read
            v[j] = lds[(sw2(((j >> 1) & 15) | (r << 4) | ((j >> 5) << 9)) << 3) + tt];

        // ---- P4: e = (j&31) | ((j>>5)<<10) | (r<<5). F3 e-bits 1..4, 10 ----
        BFLY(2) BFLY(4) BFLY(8) BFLY(16) BFLY(32)         // F3 done

        float* ob = out + ((size_t)km << 18) + t0 + tt;
        {   // + b, store.  b is two contiguous runs of 32 -> float4
            const float4* q0 = (const float4*)(bvec + (r << 5));
            const float4* q1 = (const float4*)(bvec + 1024 + (r << 5));
            #pragma unroll
            for (int qq = 0; qq < 8; ++qq) {
                float4 a = q0[qq];
                const int e0 = (r << 5) + 4*qq;
                ob[(size_t)(e0+0) * T_DIM] = v[4*qq+0] + a.x;
                ob[(size_t)(e0+1) * T_DIM] = v[4*qq+1] + a.y;
                ob[(size_t)(e0+2) * T_DIM] = v[4*qq+2] + a.z;
                ob[(size_t)(e0+3) * T_DIM] = v[4*qq+3] + a.w;
                float4 cc = q1[qq];
                const int e1 = 1024 + (r << 5) + 4*qq;
                ob[(size_t)(e1+0) * T_DIM] = v[32+4*qq+0] + cc.x;
                ob[(size_t)(e1+1) * T_DIM] = v[32+4*qq+1] + cc.y;
                ob[(size_t)(e1+2) * T_DIM] = v[32+4*qq+2] + cc.z;
                ob[(size_t)(e1+3) * T_DIM] = v[32+4*qq+3] + cc.w;
            }
        }
    }
}

extern "C" void kernel_launch(void* const* d_in, const int* in_sizes, int n_in,
                              void* d_out, int out_size, void* d_ws, size_t ws_size,
                              hipStream_t stream) {
    const float* z    = (const float*)d_in[0];
    const float* d1   = (const float*)d_in[1];
    const float* d2   = (const float*)d_in[2];
    const float* d3   = (const float*)d_in[3];
    const float* bvec = (const float*)d_in[4];
    const float* sldj = (const float*)d_in[5];
    float* out = (float*)d_out;

    // blocks 0..1023: FWHT apply (128 slabs x 8 tile-pairs, 2 passes each);
    // block 1024: sldj
    fwht_apply_kernel<<<1025, 256, 0, stream>>>(z, d1, d2, d3, bvec, sldj, out);
}

// Round 4
// 335.285 us; speedup vs baseline: 2.6938x; 2.6938x over previous
//
#include <hip/hip_runtime.h>
#include <math.h>

#define D_DIM 2048
#define T_DIM 128

// LDS: 512 rows x 16 t = 32 KiB.  Uniform swizzle: XOR row-bit0 with
// row-bit4.  Verified per-pattern: every staging/transpose access is
// <=2-way bank-aliased (free, m136).  word = swRow*16 + tt.
__device__ __forceinline__ int W(int row, int tt) {
    return ((row ^ ((row >> 4) & 1)) << 4) | tt;
}

// radix-2 butterfly over register-index bit MM (fully unrolled, constant idx)
#define BFLY(MM)                                              \
    _Pragma("unroll")                                         \
    for (int i_ = 0; i_ < 64; ++i_) {                         \
        if ((i_ & (MM)) == 0) {                               \
            float a_ = v[i_], b_ = v[i_ | (MM)];              \
            v[i_] = a_ + b_;                                  \
            v[i_ | (MM)] = a_ - b_;                           \
        }                                                     \
    }

// (512,2): R0 built 76 VGPR under this; with pf[4] prefetch expect ~95-120.
// MUST stay <128: R3 showed landing AT 128 drops to the 2-waves/SIMD bucket.
__global__ __launch_bounds__(512, 2)
void fwht_apply_kernel(const float* __restrict__ z,
                       const float* __restrict__ d1,
                       const float* __restrict__ d2,
                       const float* __restrict__ d3,
                       const float* __restrict__ bvec,
                       const float* __restrict__ sldj_in,
                       float* __restrict__ out) {
    __shared__ float lds[512 * 16];             // 32 KiB
    const int tid = threadIdx.x;

    if (blockIdx.x == 1024) {                   // ---- sldj block ----
        float acc = 0.0f;
        for (int i = tid; i < D_DIM; i += 512)
            acc += logf(fabsf(d1[i])) + logf(fabsf(d2[i])) + logf(fabsf(d3[i]));
        lds[tid] = acc;
        __syncthreads();
        #pragma unroll
        for (int sft = 256; sft > 0; sft >>= 1) {
            if (tid < sft) lds[tid] += lds[tid + sft];
            __syncthreads();
        }
        if (tid < 128)
            out[(size_t)4 * 32 * 2048 * 128 + tid] = sldj_in[tid] + lds[0];
        return;
    }

    const int r   = tid >> 4;                   // 5-bit "rest" coordinate (0..31)
    const int tt  = tid & 15;                   // t within tile (0..15)
    const int bid = blockIdx.x;
    const int km  = bid >> 3;                   // (k,m) slab — R0 mapping, measured
    const int t0  = (bid & 7) << 4;             // FETCH/WRITE == ideal 131 MB
    const float s = 0.022097086912079608f;      // 1/sqrt(2048), one per H

    const int wv   = tid >> 6;                  // wave id (0..7)
    const int lane = tid & 63;
    const int q    = lane >> 2;                 // row-within-run (0..15)
    const int c    = lane & 3;                  // float4 slot within 64B row

    const float* zb = z + ((size_t)km << 18) + t0 + (c << 2);

    float v[64];

    // ---- staging: 4 rounds partitioned by e-bits{3,4} (= r-bits{3,4}).
    // Round h holds e's with ((e>>3)&3)==h; LDS row = (e>>5)<<3 | (e&7).
    // Global: dwordx4, 16 consecutive rows x 64B per wave-instruction.
    // Prefetch: round h+1's 4 loads issued before round h's read phase,
    // so HBM latency hides under the LDS reads.
    float4 pf[4];
    #pragma unroll
    for (int i = 0; i < 4; ++i) {               // prologue: load round 0
        const int row = (wv << 6) | (i << 4) | q;
        const int e   = ((row >> 3) << 5) | (row & 7);
        pf[i] = *(const float4*)(zb + (size_t)e * T_DIM);
    }
    #pragma unroll
    for (int h = 0; h < 4; ++h) {
        #pragma unroll
        for (int i = 0; i < 4; ++i) {           // LDS write (b128)
            const int row = (wv << 6) | (i << 4) | q;
            *(float4*)&lds[W(row, c << 2)] = pf[i];
        }
        if (h < 3) {
            #pragma unroll
            for (int i = 0; i < 4; ++i) {       // prefetch round h+1
                const int row = (wv << 6) | (i << 4) | q;
                const int e   = ((row >> 3) << 5) | ((h + 1) << 3) | (row & 7);
                pf[i] = *(const float4*)(zb + (size_t)e * T_DIM);
            }
        }
        __syncthreads();
        if ((r >> 3) == h) {                    // wave-uniform: 2 waves read
            #pragma unroll
            for (int j = 0; j < 64; ++j) {
                const int e = (j << 5) | r;
                v[j] = lds[W((j << 3) | (r & 7), tt)] * (d1[e] * s);
            }
        }
        __syncthreads();
    }

    // ---- P1: e = (j<<5)|r.  F1 on e-bits 5..10 ----
    BFLY(1) BFLY(2) BFLY(4) BFLY(8) BFLY(16) BFLY(32)

    // ---- T1 (P1->P2): rounds on (e10,e0); row = (e>>1)&511.
    // write: e10=j5, e0=r0 -> threads r0==h2 write 32 j's with j5==h1.
    // read:  e10=j5, e0=j0 -> all threads read 16 j's.
    #pragma unroll
    for (int h1 = 0; h1 < 2; ++h1) {
        #pragma unroll
        for (int h2 = 0; h2 < 2; ++h2) {
            if ((r & 1) == h2) {
                #pragma unroll
                for (int jj = 0; jj < 32; ++jj) {
                    const int j = (h1 << 5) | jj;       // e=(j<<5)|r
                    lds[W((jj << 4) | (r >> 1), tt)] = v[j];
                }
            }
            __syncthreads();
            #pragma unroll
            for (int jj = 0; jj < 16; ++jj) {           // P2: e=(j&31)|(j5<<10)|(r<<5)
                const int j = (h1 << 5) | (jj << 1) | h2;
                v[j] = lds[W((r << 4) | jj, tt)];
            }
            __syncthreads();
        }
    }

    // ---- P2: e = (j&31) | ((j>>5)<<10) | (r<<5) ----
    BFLY(1) BFLY(2) BFLY(4) BFLY(8) BFLY(16)          // F1 e-bits 0..4 (F1 done)
    {   // * d2 * s : per-thread e is two contiguous runs of 32 -> float4
        const float4* q0 = (const float4*)(d2 + (r << 5));
        const float4* q1 = (const float4*)(d2 + 1024 + (r << 5));
        #pragma unroll
        for (int qq = 0; qq < 8; ++qq) {
            float4 a = q0[qq];
            v[4*qq+0] *= a.x * s; v[4*qq+1] *= a.y * s;
            v[4*qq+2] *= a.z * s; v[4*qq+3] *= a.w * s;
            float4 cc = q1[qq];
            v[32+4*qq+0] *= cc.x * s; v[32+4*qq+1] *= cc.y * s;
            v[32+4*qq+2] *= cc.z * s; v[32+4*qq+3] *= cc.w * s;
        }
    }
    BFLY(1) BFLY(2) BFLY(4) BFLY(8) BFLY(16) BFLY(32) // F2 e-bits 0..4,10

    // ---- T2 (P2->P3): rounds on (e10,e0); row = (e>>1)&511.
    // write: e10=j5, e0=j0 -> all threads write 16 j's.
    // read:  e10=r4, e0=j0 -> threads r4==h1 read 32 j's.
    #pragma unroll
    for (int h1 = 0; h1 < 2; ++h1) {
        #pragma unroll
        for (int h2 = 0; h2 < 2; ++h2) {
            #pragma unroll
            for (int jj = 0; jj < 16; ++jj) {
                const int j = (h1 << 5) | (jj << 1) | h2;
                lds[W((r << 4) | jj, tt)] = v[j];
            }
            __syncthreads();
            if ((r >> 4) == h1) {
                #pragma unroll
                for (int jj = 0; jj < 32; ++jj) {       // P3: e=((j>>1)<<5)|(j&1)|eRest
                    const int j = (jj << 1) | h2;
                    v[j] = lds[W((jj << 4) | (r & 15), tt)];
                }
            }
            __syncthreads();
        }
    }

    // ---- P3: e = ((j>>1)<<5) | (j&1) | eRest, eRest = ((r&15)<<1)|((r>>4)<<10)
    BFLY(2) BFLY(4) BFLY(8) BFLY(16) BFLY(32)         // F2 e-bits 5..9 (F2 done)
    {   // * d3 * s : (v[2m], v[2m+1]) sit at (e, e+1) -> float2
        const int eRest = ((r & 15) << 1) | ((r >> 4) << 10);
        #pragma unroll
        for (int m = 0; m < 32; ++m) {
            float2 a = *(const float2*)(d3 + ((m << 5) | eRest));
            v[2*m]   *= a.x * s;
            v[2*m+1] *= a.y * s;
        }
    }
    BFLY(2) BFLY(4) BFLY(8) BFLY(16) BFLY(32) BFLY(1) // F3 e-bits 5..9, 0

    // ---- T3 (P3->P4): rounds on (e10,e0); row = (e>>1)&511.
    // write: e10=r4, e0=j0 -> threads r4==h1 write 32 j's.
    // read:  e10=j5, e0=j0 -> all threads read 16 j's.  (mirror of T2)
    #pragma unroll
    for (int h1 = 0; h1 < 2; ++h1) {
        #pragma unroll
        for (int h2 = 0; h2 < 2; ++h2) {
            if ((r >> 4) == h1) {
                #pragma unroll
                for (int jj = 0; jj < 32; ++jj) {
                    const int j = (jj << 1) | h2;
                    lds[W((jj << 4) | (r & 15), tt)] = v[j];
                }
            }
            __syncthreads();
            #pragma unroll
            for (int jj = 0; jj < 16; ++jj) {           // P4 = P2 map
                const int j = (h1 << 5) | (jj << 1) | h2;
                v[j] = lds[W((r << 4) | jj, tt)];
            }
            if (!(h1 == 1 && h2 == 1)) __syncthreads();
        }
    }

    // ---- P4: e = (j&31) | ((j>>5)<<10) | (r<<5). F3 e-bits 1..4, 10 ----
    BFLY(2) BFLY(4) BFLY(8) BFLY(16) BFLY(32)         // F3 done

    float* ob = out + ((size_t)km << 18) + t0 + tt;
    {   // + b, store.  b is two contiguous runs of 32 -> float4
        const float4* q0 = (const float4*)(bvec + (r << 5));
        const float4* q1 = (const float4*)(bvec + 1024 + (r << 5));
        #pragma unroll
        for (int qq = 0; qq < 8; ++qq) {
            float4 a = q0[qq];
            const int e0 = (r << 5) + 4*qq;
            ob[(size_t)(e0+0) * T_DIM] = v[4*qq+0] + a.x;
            ob[(size_t)(e0+1) * T_DIM] = v[4*qq+1] + a.y;
            ob[(size_t)(e0+2) * T_DIM] = v[4*qq+2] + a.z;
            ob[(size_t)(e0+3) * T_DIM] = v[4*qq+3] + a.w;
            float4 cc = q1[qq];
            const int e1 = 1024 + (r << 5) + 4*qq;
            ob[(size_t)(e1+0) * T_DIM] = v[32+4*qq+0] + cc.x;
            ob[(size_t)(e1+1) * T_DIM] = v[32+4*qq+1] + cc.y;
            ob[(size_t)(e1+2) * T_DIM] = v[32+4*qq+2] + cc.z;
            ob[(size_t)(e1+3) * T_DIM] = v[32+4*qq+3] + cc.w;
        }
    }
}

extern "C" void kernel_launch(void* const* d_in, const int* in_sizes, int n_in,
                              void* d_out, int out_size, void* d_ws, size_t ws_size,
                              hipStream_t stream) {
    const float* z    = (const float*)d_in[0];
    const float* d1   = (const float*)d_in[1];
    const float* d2   = (const float*)d_in[2];
    const float* d3   = (const float*)d_in[3];
    const float* bvec = (const float*)d_in[4];
    const float* sldj = (const float*)d_in[5];
    float* out = (float*)d_out;

    // blocks 0..1023: FWHT apply (128 slabs x 8 t-tiles of 16); block 1024: sldj
    fwht_apply_kernel<<<1025, 512, 0, stream>>>(z, d1, d2, d3, bvec, sldj, out);
}

// Round 5
// 314.667 us; speedup vs baseline: 2.8703x; 1.0655x over previous
//
#include <hip/hip_runtime.h>
#include <math.h>

#define D_DIM 2048
#define T_DIM 128
#define TT 16

typedef __attribute__((address_space(1))) const unsigned int gu32;
typedef __attribute__((address_space(3))) unsigned int su32;

// R0-proven LDS swizzles (measured: 0 bank conflicts, absmax 0.03125)
__device__ __forceinline__ int sw1(int x) { return x ^ ((x >> 5) & 1); }
__device__ __forceinline__ int sw2(int x) { return x ^ ((x >> 4) & 1); }

// radix-2 butterfly over register-index bit MM (fully unrolled, constant idx)
#define BFLY(MM)                                              \
    _Pragma("unroll")                                         \
    for (int i_ = 0; i_ < 64; ++i_) {                         \
        if ((i_ & (MM)) == 0) {                               \
            float a_ = v[i_], b_ = v[i_ | (MM)];              \
            v[i_] = a_ + b_;                                  \
            v[i_ | (MM)] = a_ - b_;                           \
        }                                                     \
    }

// Barrier that drains LDS ops only — NOT vmcnt — so global_load_lds
// prefetch stays in flight across it (m201 pattern).  "memory" clobbers
// pin compiler ds ops on their side of the barrier.
__device__ __forceinline__ void barx() {
    asm volatile("s_waitcnt lgkmcnt(0)" ::: "memory");
    __builtin_amdgcn_s_barrier();
    asm volatile("" ::: "memory");
}
// Counted vmcnt: N newest VMEM ops may remain outstanding (in-order retire).
#define VWAIT(N) asm volatile("s_waitcnt vmcnt(" #N ")" ::: "memory")

// (512,2): empirically resident waves/SIMD == arg, VGPR cap == 256/arg.
// arg=2 -> 128-VGPR cap (we need ~85, no spill), 8 waves/CU = 1 block/CU,
// which is exactly this design's residency (160 KiB LDS/block).
__global__ __launch_bounds__(512, 2)
void fwht_apply_kernel(const float* __restrict__ z,
                       const float* __restrict__ d1,
                       const float* __restrict__ d2,
                       const float* __restrict__ d3,
                       const float* __restrict__ bvec,
                       const float* __restrict__ sldj_in,
                       float* __restrict__ out) {
    extern __shared__ float sh[];
    float* buf0 = sh;               // 64 KiB staging buffer (even half-stages)
    float* buf1 = sh + 16384;       // 64 KiB staging buffer (odd) + T-space
    float* d1l  = sh + 32768;       // d tables, pre-scaled by s (8 KiB each)
    float* d2l  = sh + 34816;
    float* d3l  = sh + 36864;
    float* bl   = sh + 38912;       // total 40960 floats = 160 KiB
    const int tid = threadIdx.x;

    if (blockIdx.x == 256) {        // ---- sldj block ----
        float acc = 0.0f;
        for (int i = tid; i < D_DIM; i += 512)
            acc += logf(fabsf(d1[i])) + logf(fabsf(d2[i])) + logf(fabsf(d3[i]));
        sh[tid] = acc;
        __syncthreads();
        #pragma unroll
        for (int sft = 256; sft > 0; sft >>= 1) {
            if (tid < sft) sh[tid] += sh[tid + sft];
            __syncthreads();
        }
        if (tid < 128)
            out[(size_t)4 * 32 * 2048 * 128 + tid] = sldj_in[tid] + sh[0];
        return;
    }

    const int r    = tid >> 4;      // 5-bit "rest" coordinate (0..31)
    const int tt   = tid & 15;      // t within tile (0..15)
    const int b    = blockIdx.x;    // block b owns km-slab b>>1's t-tiles
    const int wid  = tid >> 6;      // (tiles 4b..4b+3: both 64B halves of
    const int lane = tid & 63;      //  every 128B out-line in ONE block)
    const int q    = lane >> 2;     // row-within-run (0..15)
    const int c    = lane & 3;      // float4 slot within 64B row
    const float s  = 0.022097086912079608f;   // 1/sqrt(2048)

    // ---- d tables -> LDS, pre-scaled (keeps vmcnt clean for prefetch:
    // in-order vmcnt means any global d-load wait would drain gl_lds too).
    for (int k = tid; k < D_DIM; k += 512) {
        d1l[k] = d1[k] * s;
        d2l[k] = d2[k] * s;
        d3l[k] = d3[k] * s;
        bl[k]  = bvec[k];
    }

    // Issue one half-tile (64 KiB) of async loads: 8 gl_lds per wave.
    // LDS layout word = ((n<<4)|q)*16 + 4c  ==  base(n) + lane*16B: linear
    // in lane order as gl_lds requires.  Global: 16 rows x 64B per instr
    // (R0's exact address set -> FETCH stays ideal).
    auto issue = [&](float* buf, int tau, int h) {
        const float* zs = z + ((size_t)(tau >> 3) << 18) + ((tau & 7) << 4) + (c << 2);
        #pragma unroll
        for (int i = 0; i < 8; ++i) {
            const int n = (wid << 3) | i;
            const int e = (n << 5) | (h << 4) | q;
            __builtin_amdgcn_global_load_lds((gu32*)(zs + (size_t)e * T_DIM),
                                             (su32*)(buf + (n << 8)), 16, 0, 0);
        }
    };

    issue(buf0, b << 2, 0);                 // prologue: stage 0

    #pragma unroll 1
    for (int ti = 0; ti < 4; ++ti) {
        const int tau = (b << 2) | ti;
        float v[64];

        // ---- half 0: read buf0 (stage 2ti), prefetch stage 2ti+1 ----
        barx();                             // prior tile's T3 reads done
        issue(buf1, tau, 1);
        VWAIT(8);                           // buf0 landed; old stores drained
        barx();                             // cross-wave visibility
        if (r < 16) {
            #pragma unroll
            for (int j = 0; j < 64; ++j)
                v[j] = buf0[(((j << 4) | (r & 15)) << 4) + tt] * d1l[(j << 5) | r];
        }
        // ---- half 1: read buf1 (stage 2ti+1), prefetch stage 2ti+2 ----
        barx();                             // half-0 readers done (buf0 reloads)
        if (ti < 3) { issue(buf0, tau + 1, 0); VWAIT(8); }
        else        { VWAIT(0); }
        barx();
        if (r >= 16) {
            #pragma unroll
            for (int j = 0; j < 64; ++j)
                v[j] = buf1[(((j << 4) | (r & 15)) << 4) + tt] * d1l[(j << 5) | r];
        }
        barx();                             // readers done before T1 writes buf1

        float* tl = buf1;                   // T-space (buf0 receives prefetch)

        // ---- P1: e = (j<<5)|r.  F1 on e-bits 5..10 ----
        BFLY(1) BFLY(2) BFLY(4) BFLY(8) BFLY(16) BFLY(32)

        // ---- T1: partition e-bit10 (= j5 on both sides). e' = e & 1023 ----
        #pragma unroll
        for (int j = 0; j < 32; ++j)
            tl[sw1((j << 5) | r) * TT + tt] = v[j];
        barx();
        #pragma unroll
        for (int j = 0; j < 32; ++j)
            v[j] = tl[sw1(j | (r << 5)) * TT + tt];
        barx();
        #pragma unroll
        for (int j = 32; j < 64; ++j)
            tl[sw1(((j & 31) << 5) | r) * TT + tt] = v[j];
        barx();
        #pragma unroll
        for (int j = 32; j < 64; ++j)
            v[j] = tl[sw1((j & 31) | (r << 5)) * TT + tt];
        barx();

        // ---- P2: e = (j&31) | ((j>>5)<<10) | (r<<5) ----
        BFLY(1) BFLY(2) BFLY(4) BFLY(8) BFLY(16)          // F1 done
        {   // * d2 (pre-scaled): two contiguous runs of 32 -> float4
            const float4* q0 = (const float4*)(d2l + (r << 5));
            const float4* q1 = (const float4*)(d2l + 1024 + (r << 5));
            #pragma unroll
            for (int qq = 0; qq < 8; ++qq) {
                float4 a = q0[qq];
                v[4*qq+0] *= a.x; v[4*qq+1] *= a.y;
                v[4*qq+2] *= a.z; v[4*qq+3] *= a.w;
                float4 cc = q1[qq];
                v[32+4*qq+0] *= cc.x; v[32+4*qq+1] *= cc.y;
                v[32+4*qq+2] *= cc.z; v[32+4*qq+3] *= cc.w;
            }
        }
        BFLY(1) BFLY(2) BFLY(4) BFLY(8) BFLY(16) BFLY(32) // F2 e-bits 0..4,10

        // ---- T2: partition e-bit0 (= j0 both sides). e' = e >> 1 ----
        #pragma unroll
        for (int j = 0; j < 64; j += 2)
            tl[sw2(((j >> 1) & 15) | (r << 4) | ((j >> 5) << 9)) * TT + tt] = v[j];
        barx();
        #pragma unroll
        for (int j = 0; j < 64; j += 2)
            v[j] = tl[sw2((((j >> 1) & 31) << 4) | (r & 15) | ((r >> 4) << 9)) * TT + tt];
        barx();
        #pragma unroll
        for (int j = 1; j < 64; j += 2)
            tl[sw2(((j >> 1) & 15) | (r << 4) | ((j >> 5) << 9)) * TT + tt] = v[j];
        barx();
        #pragma unroll
        for (int j = 1; j < 64; j += 2)
            v[j] = tl[sw2((((j >> 1) & 31) << 4) | (r & 15) | ((r >> 4) << 9)) * TT + tt];
        barx();

        // ---- P3: e = ((j>>1)<<5)|(j&1)|eRest, eRest = ((r&15)<<1)|((r>>4)<<10)
        BFLY(2) BFLY(4) BFLY(8) BFLY(16) BFLY(32)         // F2 done
        {   // * d3 (pre-scaled): (v[2m], v[2m+1]) at (e, e+1) -> float2
            const int eRest = ((r & 15) << 1) | ((r >> 4) << 10);
            #pragma unroll
            for (int m = 0; m < 32; ++m) {
                float2 a = *(const float2*)(d3l + ((m << 5) | eRest));
                v[2*m]   *= a.x;
                v[2*m+1] *= a.y;
            }
        }
        BFLY(2) BFLY(4) BFLY(8) BFLY(16) BFLY(32) BFLY(1) // F3 e-bits 5..9, 0

        // ---- T3: partition e-bit0. e' = e >> 1 (mirror of T2) ----
        #pragma unroll
        for (int j = 0; j < 64; j += 2)
            tl[sw2((((j >> 1) & 31) << 4) | (r & 15) | ((r >> 4) << 9)) * TT + tt] = v[j];
        barx();
        #pragma unroll
        for (int j = 0; j < 64; j += 2)
            v[j] = tl[sw2(((j >> 1) & 15) | (r << 4) | ((j >> 5) << 9)) * TT + tt];
        barx();
        #pragma unroll
        for (int j = 1; j < 64; j += 2)
            tl[sw2((((j >> 1) & 31) << 4) | (r & 15) | ((r >> 4) << 9)) * TT + tt] = v[j];
        barx();
        #pragma unroll
        for (int j = 1; j < 64; j += 2)
            v[j] = tl[sw2(((j >> 1) & 15) | (r << 4) | ((j >> 5) << 9)) * TT + tt];
        // (no trailing barrier: next tile's loop-top barx covers buf1 reuse)

        // ---- P4: e = (j&31) | ((j>>5)<<10) | (r<<5). F3 e-bits 1..4, 10 ----
        BFLY(2) BFLY(4) BFLY(8) BFLY(16) BFLY(32)         // F3 done

        float* ob = out + ((size_t)(tau >> 3) << 18) + ((tau & 7) << 4) + tt;
        {   // + b, store.  b: two contiguous runs of 32 -> float4 from LDS
            const float4* q0 = (const float4*)(bl + (r << 5));
            const float4* q1 = (const float4*)(bl + 1024 + (r << 5));
            #pragma unroll
            for (int qq = 0; qq < 8; ++qq) {
                float4 a = q0[qq];
                const int e0 = (r << 5) + 4*qq;
                ob[(size_t)(e0+0) * T_DIM] = v[4*qq+0] + a.x;
                ob[(size_t)(e0+1) * T_DIM] = v[4*qq+1] + a.y;
                ob[(size_t)(e0+2) * T_DIM] = v[4*qq+2] + a.z;
                ob[(size_t)(e0+3) * T_DIM] = v[4*qq+3] + a.w;
                float4 cc = q1[qq];
                const int e1 = 1024 + (r << 5) + 4*qq;
                ob[(size_t)(e1+0) * T_DIM] = v[32+4*qq+0] + cc.x;
                ob[(size_t)(e1+1) * T_DIM] = v[32+4*qq+1] + cc.y;
                ob[(size_t)(e1+2) * T_DIM] = v[32+4*qq+2] + cc.z;
                ob[(size_t)(e1+3) * T_DIM] = v[32+4*qq+3] + cc.w;
            }
        }
    }
}

extern "C" void kernel_launch(void* const* d_in, const int* in_sizes, int n_in,
                              void* d_out, int out_size, void* d_ws, size_t ws_size,
                              hipStream_t stream) {
    const float* z    = (const float*)d_in[0];
    const float* d1   = (const float*)d_in[1];
    const float* d2   = (const float*)d_in[2];
    const float* d3   = (const float*)d_in[3];
    const float* bvec = (const float*)d_in[4];
    const float* sldj = (const float*)d_in[5];
    float* out = (float*)d_out;

    // 160 KiB dynamic LDS needs the attribute raised past the 64 KiB default.
    hipFuncSetAttribute((const void*)fwht_apply_kernel,
                        hipFuncAttributeMaxDynamicSharedMemorySize, 163840);

    // blocks 0..255: one per CU, 4 t-tiles of one km-slab each, double-
    // buffered async staging; block 256: sldj
    fwht_apply_kernel<<<257, 512, 163840, stream>>>(z, d1, d2, d3, bvec, sldj, out);
}